// Round 1
// baseline (704.544 us; speedup 1.0000x reference)
//
#include <hip/hip_runtime.h>
#include <stdint.h>

#define NB 16
#define NT 2048
#define ND 64

typedef __attribute__((ext_vector_type(8))) short bf16x8;
typedef __attribute__((ext_vector_type(4))) float f32x4;

__device__ __forceinline__ unsigned short f2bf(float f) {
    union { float f; unsigned u; } v; v.f = f;
    unsigned r = v.u + 0x7fffu + ((v.u >> 16) & 1u);   // round-to-nearest-even
    return (unsigned short)(r >> 16);
}

__device__ __forceinline__ bf16x8 pack8(float4 a, float4 b) {
    union { unsigned short s[8]; bf16x8 v; } u;
    u.s[0] = f2bf(a.x); u.s[1] = f2bf(a.y); u.s[2] = f2bf(a.z); u.s[3] = f2bf(a.w);
    u.s[4] = f2bf(b.x); u.s[5] = f2bf(b.y); u.s[6] = f2bf(b.z); u.s[7] = f2bf(b.w);
    return u.v;
}

// One WG: 16 query rows of one batch. 4 waves, each owns 512 keys.
// Phase 1: S^T = K·Q^T (MFMA, lane holds qrow=lane&15, 4 consecutive keys)
//          E = exp(S*scale + bias) kept in 128 VGPRs; rowsum accumulated.
// Phase 2: rowsum reduce (shfl_xor across quads, LDS across waves).
// Phase 3: p = E/rowsum -> dwordx4 attn stores; LDS repack to B-frag layout;
//          O^T += V^T-frags · P-frags (MFMA); V read strided from L2-resident V.
// Epilogue: cross-wave O reduce via atomicAdd (output pre-zeroed by memset).
__global__ __launch_bounds__(256, 2)
void attn_fused(const float* __restrict__ Q, const float* __restrict__ K,
                const float* __restrict__ V, const float* __restrict__ Bias,
                float* __restrict__ Out, float* __restrict__ Attn)
{
    const int b  = blockIdx.y;
    const int q0 = blockIdx.x * 16;
    const int tid  = threadIdx.x;
    const int w    = tid >> 6;     // wave 0..3
    const int lane = tid & 63;
    const int n  = lane & 15;      // qrow (phase1 C-col / phase3 B-n) or V-d row
    const int qd = lane >> 4;      // quad 0..3

    const int kw0 = w * 512;       // this wave's key range base

    __shared__ float s_rs[4][16];
    __shared__ __align__(16) unsigned char s_rp[4][16 * 80]; // per-wave repack, 80B row stride (pad)

    const float* Qb = Q + ((size_t)b * NT + q0) * ND;
    const float* Kb = K + (size_t)b * NT * ND;
    const float* Vb = V + (size_t)b * NT * ND;
    const float* Bb = Bias + ((size_t)b * NT + q0) * NT;
    float* Ab = Attn + ((size_t)b * NT + q0) * NT;
    float* Ob = Out  + ((size_t)b * NT + q0) * ND;

    // Q as B-operand: lane holds Q[q0 + n][qd*8 + j], two k-halves (D=64)
    bf16x8 qf0, qf1;
    {
        const float* qp = Qb + n * ND + qd * 8;
        qf0 = pack8(*(const float4*)qp,        *(const float4*)(qp + 4));
        qf1 = pack8(*(const float4*)(qp + 32), *(const float4*)(qp + 36));
    }

    float ev[32][4];   // unnormalized exp, 4 consecutive keys per tile
    float rs = 0.f;

#pragma unroll
    for (int t = 0; t < 32; ++t) {
        const int key0 = kw0 + 16 * t;
        // K as A-operand: lane holds K[key0 + n][qd*8 + j]
        const float* kp = Kb + (size_t)(key0 + n) * ND + qd * 8;
        bf16x8 kf0 = pack8(*(const float4*)kp,        *(const float4*)(kp + 4));
        bf16x8 kf1 = pack8(*(const float4*)(kp + 32), *(const float4*)(kp + 36));
        f32x4 acc = {0.f, 0.f, 0.f, 0.f};
        acc = __builtin_amdgcn_mfma_f32_16x16x32_bf16(kf0, qf0, acc, 0, 0, 0);
        acc = __builtin_amdgcn_mfma_f32_16x16x32_bf16(kf1, qf1, acc, 0, 0, 0);
        // C/D layout: col = n = qrow, row = qd*4 + r = key-within-tile (consecutive!)
        float4 bs = *(const float4*)(Bb + (size_t)n * NT + key0 + qd * 4);
        float e0 = __expf(acc[0] * 0.125f + bs.x);
        float e1 = __expf(acc[1] * 0.125f + bs.y);
        float e2 = __expf(acc[2] * 0.125f + bs.z);
        float e3 = __expf(acc[3] * 0.125f + bs.w);
        ev[t][0] = e0; ev[t][1] = e1; ev[t][2] = e2; ev[t][3] = e3;
        rs += (e0 + e1) + (e2 + e3);
    }

    // rowsum for qrow = n: reduce across quads, then across waves
    rs += __shfl_xor(rs, 16, 64);
    rs += __shfl_xor(rs, 32, 64);
    if (lane < 16) s_rs[w][lane] = rs;
    __syncthreads();
    const float tot = (s_rs[0][n] + s_rs[1][n]) + (s_rs[2][n] + s_rs[3][n]);
    const float inv = 1.0f / tot;

    f32x4 oacc[4];
#pragma unroll
    for (int dt = 0; dt < 4; ++dt) oacc[dt] = (f32x4){0.f, 0.f, 0.f, 0.f};

    unsigned char* rp = &s_rp[w][0];

#pragma unroll
    for (int c = 0; c < 16; ++c) {
        const int kbase = kw0 + 32 * c;   // 32-key chunk = 2 tiles
#pragma unroll
        for (int tt = 0; tt < 2; ++tt) {
            const int t = 2 * c + tt;
            float p0 = ev[t][0] * inv;
            float p1 = ev[t][1] * inv;
            float p2 = ev[t][2] * inv;
            float p3 = ev[t][3] * inv;
            float4 pv; pv.x = p0; pv.y = p1; pv.z = p2; pv.w = p3;
            // attn store: 4 consecutive keys at row n -> full 64B lines per wave inst
            *(float4*)(Ab + (size_t)n * NT + kbase + 16 * tt + qd * 4) = pv;
            // stash bf16 p into per-wave repack buffer at [qrow][key-within-chunk]
            union { unsigned short s[4]; unsigned long long ll; } pu;
            pu.s[0] = f2bf(p0); pu.s[1] = f2bf(p1);
            pu.s[2] = f2bf(p2); pu.s[3] = f2bf(p3);
            *(unsigned long long*)(rp + n * 80 + (16 * tt + 4 * qd) * 2) = pu.ll;
        }
        __syncthreads();   // make repack visible (cross-lane within wave; keep waves lockstep)
        // P as B-operand: lane holds P[qrow = n][kbase + qd*8 + j]
        bf16x8 pf;
        {
            union { uint4 u; bf16x8 v; } uu;
            uu.u = *(const uint4*)(rp + n * 80 + qd * 16);
            pf = uu.v;
        }
#pragma unroll
        for (int dt = 0; dt < 4; ++dt) {
            // V^T as A-operand: lane holds V[kbase + qd*8 + j][d = dt*16 + n]
            const int d = dt * 16 + n;
            const float* vp = Vb + (size_t)(kbase + qd * 8) * ND + d;
            float4 va, vb4;
            va.x  = vp[0];   va.y  = vp[64];  va.z  = vp[128]; va.w  = vp[192];
            vb4.x = vp[256]; vb4.y = vp[320]; vb4.z = vp[384]; vb4.w = vp[448];
            bf16x8 vf = pack8(va, vb4);
            oacc[dt] = __builtin_amdgcn_mfma_f32_16x16x32_bf16(vf, pf, oacc[dt], 0, 0, 0);
        }
        __syncthreads();   // protect repack buffer before next chunk's writes
    }

    // O^T C-layout: col = n = qrow, row = qd*4 + r = d-within-tile.
    // Waves hold partials over disjoint keys -> reduce via device atomics.
#pragma unroll
    for (int dt = 0; dt < 4; ++dt)
#pragma unroll
        for (int r = 0; r < 4; ++r)
            atomicAdd(Ob + (size_t)n * ND + dt * 16 + qd * 4 + r, oacc[dt][r]);
}

extern "C" void kernel_launch(void* const* d_in, const int* in_sizes, int n_in,
                              void* d_out, int out_size, void* d_ws, size_t ws_size,
                              hipStream_t stream)
{
    const float* q    = (const float*)d_in[0];
    const float* k    = (const float*)d_in[1];
    const float* v    = (const float*)d_in[2];
    const float* bias = (const float*)d_in[3];
    float* out  = (float*)d_out;                      // [B,T,D]
    float* attn = out + (size_t)NB * NT * ND;         // [B,T,T]

    // zero the output head (atomicAdd epilogue accumulates into it)
    hipMemsetAsync(out, 0, (size_t)NB * NT * ND * sizeof(float), stream);

    dim3 grid(NT / 16, NB);
    attn_fused<<<grid, 256, 0, stream>>>(q, k, v, bias, out, attn);
}

// Round 2
// 680.882 us; speedup vs baseline: 1.0348x; 1.0348x over previous
//
#include <hip/hip_runtime.h>
#include <stdint.h>

#define NB 16
#define NT 2048
#define ND 64

typedef __attribute__((ext_vector_type(8))) short bf16x8;
typedef __attribute__((ext_vector_type(4))) float f32x4;

__device__ __forceinline__ unsigned short f2bf(float f) {
    union { float f; unsigned u; } v; v.f = f;
    unsigned r = v.u + 0x7fffu + ((v.u >> 16) & 1u);   // RNE
    return (unsigned short)(r >> 16);
}

// ---------------- K0: dtype prep ----------------
// y=0: Q->bf16 row-major; y=1: K->bf16 row-major; y=2: V->bf16 transposed VT[b][d][t]
__global__ __launch_bounds__(256) void prep_k(const float* __restrict__ Q,
                                              const float* __restrict__ K,
                                              const float* __restrict__ V,
                                              unsigned short* __restrict__ qbf,
                                              unsigned short* __restrict__ kbf,
                                              unsigned short* __restrict__ vt)
{
    const size_t i = (size_t)blockIdx.x * 256 + threadIdx.x;   // float4 index
    const int which = blockIdx.y;
    if (which == 2) {
        float4 v4 = ((const float4*)V)[i];
        const int d4 = (int)(i & 15);
        const int t  = (int)((i >> 4) & (NT - 1));
        const int b  = (int)(i >> 15);
        unsigned short* base = vt + ((size_t)b * ND + d4 * 4) * NT + t;
        base[0]      = f2bf(v4.x);
        base[NT]     = f2bf(v4.y);
        base[2 * NT] = f2bf(v4.z);
        base[3 * NT] = f2bf(v4.w);
    } else {
        const float4* src = (which == 0) ? (const float4*)Q : (const float4*)K;
        unsigned short* dst = (which == 0) ? qbf : kbf;
        float4 v4 = src[i];
        union { unsigned short s[4]; unsigned long long ll; } u;
        u.s[0] = f2bf(v4.x); u.s[1] = f2bf(v4.y);
        u.s[2] = f2bf(v4.z); u.s[3] = f2bf(v4.w);
        *(unsigned long long*)(dst + 4 * i) = u.ll;
    }
}

// ---------------- K1: rowsum ----------------
// WG = 16 query rows x 2048 keys (wave owns 512). Pure bias stream + MFMA + exp.
__global__ __launch_bounds__(256, 4)
void rowsum_k(const unsigned short* __restrict__ qbf,
              const unsigned short* __restrict__ kbf,
              const float* __restrict__ Bias,
              float* __restrict__ rsum)
{
    const int b = blockIdx.y, q0 = blockIdx.x * 16;
    const int tid = threadIdx.x, w = tid >> 6, lane = tid & 63;
    const int n = lane & 15, qd = lane >> 4;
    const int kw0 = w * 512;
    __shared__ float s_rs[4][16];

    const unsigned short* qp = qbf + ((size_t)(b * NT + q0 + n)) * ND + qd * 8;
    const bf16x8 qf0 = *(const bf16x8*)qp;
    const bf16x8 qf1 = *(const bf16x8*)(qp + 32);
    const float* Bb = Bias + ((size_t)b * NT + q0 + n) * NT;

    float rs = 0.f;
#pragma unroll 4
    for (int t = 0; t < 32; ++t) {
        const int key0 = kw0 + 16 * t;
        const unsigned short* kp = kbf + ((size_t)(b * NT + key0 + n)) * ND + qd * 8;
        bf16x8 kf0 = *(const bf16x8*)kp;
        bf16x8 kf1 = *(const bf16x8*)(kp + 32);
        f32x4 acc = {0.f, 0.f, 0.f, 0.f};
        acc = __builtin_amdgcn_mfma_f32_16x16x32_bf16(kf0, qf0, acc, 0, 0, 0);
        acc = __builtin_amdgcn_mfma_f32_16x16x32_bf16(kf1, qf1, acc, 0, 0, 0);
        float4 bs = *(const float4*)(Bb + key0 + qd * 4);
        float e0 = __expf(__builtin_fmaf(acc[0], 0.125f, bs.x));
        float e1 = __expf(__builtin_fmaf(acc[1], 0.125f, bs.y));
        float e2 = __expf(__builtin_fmaf(acc[2], 0.125f, bs.z));
        float e3 = __expf(__builtin_fmaf(acc[3], 0.125f, bs.w));
        rs += (e0 + e1) + (e2 + e3);
    }
    rs += __shfl_xor(rs, 16, 64);
    rs += __shfl_xor(rs, 32, 64);
    if (lane < 16) s_rs[w][lane] = rs;
    __syncthreads();
    if (tid < 16)
        rsum[b * NT + q0 + tid] =
            (s_rs[0][tid] + s_rs[1][tid]) + (s_rs[2][tid] + s_rs[3][tid]);
}

// ---------------- K2: recompute + normalize + attn store + PV ----------------
__global__ __launch_bounds__(256, 4)
void attn_pv_k(const unsigned short* __restrict__ qbf,
               const unsigned short* __restrict__ kbf,
               const unsigned short* __restrict__ vt,
               const float* __restrict__ Bias,
               const float* __restrict__ rsum,
               float* __restrict__ Out,
               float* __restrict__ Attn)
{
    const int b = blockIdx.y, q0 = blockIdx.x * 16;
    const int tid = threadIdx.x, w = tid >> 6, lane = tid & 63;
    const int n = lane & 15, qd = lane >> 4;
    const int kw0 = w * 512;

    __shared__ __align__(16) unsigned char s_rp[4][16 * 80]; // per-wave P repack
    __shared__ float s_o[4 * 16 * 68];                       // cross-wave O reduce (pad 68)

    const unsigned short* qp = qbf + ((size_t)(b * NT + q0 + n)) * ND + qd * 8;
    const bf16x8 qf0 = *(const bf16x8*)qp;
    const bf16x8 qf1 = *(const bf16x8*)(qp + 32);
    const float* Bb = Bias + ((size_t)b * NT + q0 + n) * NT;
    float* Ab = Attn + ((size_t)b * NT + q0 + n) * NT;
    const float inv = 1.0f / rsum[b * NT + q0 + n];
    const unsigned short* vtb = vt + (size_t)b * ND * NT + (size_t)n * NT;

    f32x4 oacc[4];
#pragma unroll
    for (int dt = 0; dt < 4; ++dt) oacc[dt] = (f32x4){0.f, 0.f, 0.f, 0.f};

    unsigned char* rp = &s_rp[w][0];

#pragma unroll 2
    for (int c = 0; c < 16; ++c) {
        const int kbase = kw0 + 32 * c;
        // QK^T for 2 tiles of 16 keys (bitwise-identical to K1's)
        const unsigned short* kpA = kbf + ((size_t)(b * NT + kbase + n)) * ND + qd * 8;
        bf16x8 kA0 = *(const bf16x8*)kpA;
        bf16x8 kA1 = *(const bf16x8*)(kpA + 32);
        bf16x8 kB0 = *(const bf16x8*)(kpA + 16 * ND);
        bf16x8 kB1 = *(const bf16x8*)(kpA + 16 * ND + 32);
        f32x4 aA = {0.f, 0.f, 0.f, 0.f}, aB = {0.f, 0.f, 0.f, 0.f};
        aA = __builtin_amdgcn_mfma_f32_16x16x32_bf16(kA0, qf0, aA, 0, 0, 0);
        aA = __builtin_amdgcn_mfma_f32_16x16x32_bf16(kA1, qf1, aA, 0, 0, 0);
        aB = __builtin_amdgcn_mfma_f32_16x16x32_bf16(kB0, qf0, aB, 0, 0, 0);
        aB = __builtin_amdgcn_mfma_f32_16x16x32_bf16(kB1, qf1, aB, 0, 0, 0);
        float4 b0 = *(const float4*)(Bb + kbase + qd * 4);
        float4 b1 = *(const float4*)(Bb + kbase + 16 + qd * 4);
        float p0 = __expf(__builtin_fmaf(aA[0], 0.125f, b0.x)) * inv;
        float p1 = __expf(__builtin_fmaf(aA[1], 0.125f, b0.y)) * inv;
        float p2 = __expf(__builtin_fmaf(aA[2], 0.125f, b0.z)) * inv;
        float p3 = __expf(__builtin_fmaf(aA[3], 0.125f, b0.w)) * inv;
        float p4 = __expf(__builtin_fmaf(aB[0], 0.125f, b1.x)) * inv;
        float p5 = __expf(__builtin_fmaf(aB[1], 0.125f, b1.y)) * inv;
        float p6 = __expf(__builtin_fmaf(aB[2], 0.125f, b1.z)) * inv;
        float p7 = __expf(__builtin_fmaf(aB[3], 0.125f, b1.w)) * inv;
        float4 s0; s0.x = p0; s0.y = p1; s0.z = p2; s0.w = p3;
        float4 s1; s1.x = p4; s1.y = p5; s1.z = p6; s1.w = p7;
        *(float4*)(Ab + kbase + qd * 4) = s0;
        *(float4*)(Ab + kbase + 16 + qd * 4) = s1;
        // intra-wave repack C-layout -> B-operand layout (no barrier: DS-pipe is
        // in-order per wave; fences order LDS ops without draining vmcnt)
        union { unsigned short s[4]; unsigned long long ll; } u0, u1;
        u0.s[0] = f2bf(p0); u0.s[1] = f2bf(p1); u0.s[2] = f2bf(p2); u0.s[3] = f2bf(p3);
        u1.s[0] = f2bf(p4); u1.s[1] = f2bf(p5); u1.s[2] = f2bf(p6); u1.s[3] = f2bf(p7);
        *(unsigned long long*)(rp + n * 80 + qd * 8) = u0.ll;
        *(unsigned long long*)(rp + n * 80 + 32 + qd * 8) = u1.ll;
        __builtin_amdgcn_fence(__ATOMIC_ACQ_REL, "workgroup");
        bf16x8 pf = *(const bf16x8*)(rp + n * 80 + qd * 16);
        __builtin_amdgcn_fence(__ATOMIC_ACQ_REL, "workgroup");
        // O^T += V^T-frags . P^T-frags  (VT loads are contiguous dwordx4, L2-hot)
        const unsigned short* vp = vtb + kbase + qd * 8;
#pragma unroll
        for (int dt = 0; dt < 4; ++dt) {
            bf16x8 vf = *(const bf16x8*)(vp + (size_t)dt * 16 * NT);
            oacc[dt] = __builtin_amdgcn_mfma_f32_16x16x32_bf16(vf, pf, oacc[dt], 0, 0, 0);
        }
    }

    // cross-wave O reduction in LDS, then coalesced float4 store
#pragma unroll
    for (int dt = 0; dt < 4; ++dt) {
        float4 t; t.x = oacc[dt][0]; t.y = oacc[dt][1]; t.z = oacc[dt][2]; t.w = oacc[dt][3];
        *(float4*)&s_o[(w * 16 + n) * 68 + dt * 16 + qd * 4] = t;
    }
    __syncthreads();
    {
        const int row = tid >> 4, d4 = (tid & 15) * 4;
        float4 o0 = *(const float4*)&s_o[(0 * 16 + row) * 68 + d4];
        float4 o1 = *(const float4*)&s_o[(1 * 16 + row) * 68 + d4];
        float4 o2 = *(const float4*)&s_o[(2 * 16 + row) * 68 + d4];
        float4 o3 = *(const float4*)&s_o[(3 * 16 + row) * 68 + d4];
        float4 o;
        o.x = (o0.x + o1.x) + (o2.x + o3.x);
        o.y = (o0.y + o1.y) + (o2.y + o3.y);
        o.z = (o0.z + o1.z) + (o2.z + o3.z);
        o.w = (o0.w + o1.w) + (o2.w + o3.w);
        *(float4*)(Out + ((size_t)b * NT + q0 + row) * ND + d4) = o;
    }
}

// ---------------- fallback: round-1 fused kernel (used only if ws too small) ----
typedef bf16x8 bf16x8_t;
__device__ __forceinline__ bf16x8 pack8(float4 a, float4 b) {
    union { unsigned short s[8]; bf16x8 v; } u;
    u.s[0] = f2bf(a.x); u.s[1] = f2bf(a.y); u.s[2] = f2bf(a.z); u.s[3] = f2bf(a.w);
    u.s[4] = f2bf(b.x); u.s[5] = f2bf(b.y); u.s[6] = f2bf(b.z); u.s[7] = f2bf(b.w);
    return u.v;
}
__global__ __launch_bounds__(256, 2)
void attn_fused(const float* __restrict__ Q, const float* __restrict__ K,
                const float* __restrict__ V, const float* __restrict__ Bias,
                float* __restrict__ Out, float* __restrict__ Attn)
{
    const int b  = blockIdx.y;
    const int q0 = blockIdx.x * 16;
    const int tid  = threadIdx.x;
    const int w    = tid >> 6;
    const int lane = tid & 63;
    const int n  = lane & 15;
    const int qd = lane >> 4;
    const int kw0 = w * 512;
    __shared__ float s_rs[4][16];
    __shared__ __align__(16) unsigned char s_rp[4][16 * 80];
    const float* Qb = Q + ((size_t)b * NT + q0) * ND;
    const float* Kb = K + (size_t)b * NT * ND;
    const float* Vb = V + (size_t)b * NT * ND;
    const float* Bb = Bias + ((size_t)b * NT + q0) * NT;
    float* Ab = Attn + ((size_t)b * NT + q0) * NT;
    float* Ob = Out  + ((size_t)b * NT + q0) * ND;
    bf16x8 qf0, qf1;
    {
        const float* qp = Qb + n * ND + qd * 8;
        qf0 = pack8(*(const float4*)qp,        *(const float4*)(qp + 4));
        qf1 = pack8(*(const float4*)(qp + 32), *(const float4*)(qp + 36));
    }
    float ev[32][4];
    float rs = 0.f;
#pragma unroll
    for (int t = 0; t < 32; ++t) {
        const int key0 = kw0 + 16 * t;
        const float* kp = Kb + (size_t)(key0 + n) * ND + qd * 8;
        bf16x8 kf0 = pack8(*(const float4*)kp,        *(const float4*)(kp + 4));
        bf16x8 kf1 = pack8(*(const float4*)(kp + 32), *(const float4*)(kp + 36));
        f32x4 acc = {0.f, 0.f, 0.f, 0.f};
        acc = __builtin_amdgcn_mfma_f32_16x16x32_bf16(kf0, qf0, acc, 0, 0, 0);
        acc = __builtin_amdgcn_mfma_f32_16x16x32_bf16(kf1, qf1, acc, 0, 0, 0);
        float4 bs = *(const float4*)(Bb + (size_t)n * NT + key0 + qd * 4);
        float e0 = __expf(acc[0] * 0.125f + bs.x);
        float e1 = __expf(acc[1] * 0.125f + bs.y);
        float e2 = __expf(acc[2] * 0.125f + bs.z);
        float e3 = __expf(acc[3] * 0.125f + bs.w);
        ev[t][0] = e0; ev[t][1] = e1; ev[t][2] = e2; ev[t][3] = e3;
        rs += (e0 + e1) + (e2 + e3);
    }
    rs += __shfl_xor(rs, 16, 64);
    rs += __shfl_xor(rs, 32, 64);
    if (lane < 16) s_rs[w][lane] = rs;
    __syncthreads();
    const float tot = (s_rs[0][n] + s_rs[1][n]) + (s_rs[2][n] + s_rs[3][n]);
    const float inv = 1.0f / tot;
    f32x4 oacc[4];
#pragma unroll
    for (int dt = 0; dt < 4; ++dt) oacc[dt] = (f32x4){0.f, 0.f, 0.f, 0.f};
    unsigned char* rp = &s_rp[w][0];
#pragma unroll
    for (int c = 0; c < 16; ++c) {
        const int kbase = kw0 + 32 * c;
#pragma unroll
        for (int tt = 0; tt < 2; ++tt) {
            const int t = 2 * c + tt;
            float p0 = ev[t][0] * inv;
            float p1 = ev[t][1] * inv;
            float p2 = ev[t][2] * inv;
            float p3 = ev[t][3] * inv;
            float4 pv; pv.x = p0; pv.y = p1; pv.z = p2; pv.w = p3;
            *(float4*)(Ab + (size_t)n * NT + kbase + 16 * tt + qd * 4) = pv;
            union { unsigned short s[4]; unsigned long long ll; } pu;
            pu.s[0] = f2bf(p0); pu.s[1] = f2bf(p1);
            pu.s[2] = f2bf(p2); pu.s[3] = f2bf(p3);
            *(unsigned long long*)(rp + n * 80 + (16 * tt + 4 * qd) * 2) = pu.ll;
        }
        __syncthreads();
        bf16x8 pf;
        {
            union { uint4 u; bf16x8 v; } uu;
            uu.u = *(const uint4*)(rp + n * 80 + qd * 16);
            pf = uu.v;
        }
#pragma unroll
        for (int dt = 0; dt < 4; ++dt) {
            const int d = dt * 16 + n;
            const float* vp = Vb + (size_t)(kbase + qd * 8) * ND + d;
            float4 va, vb4;
            va.x  = vp[0];   va.y  = vp[64];  va.z  = vp[128]; va.w  = vp[192];
            vb4.x = vp[256]; vb4.y = vp[320]; vb4.z = vp[384]; vb4.w = vp[448];
            bf16x8 vf = pack8(va, vb4);
            oacc[dt] = __builtin_amdgcn_mfma_f32_16x16x32_bf16(vf, pf, oacc[dt], 0, 0, 0);
        }
        __syncthreads();
    }
#pragma unroll
    for (int dt = 0; dt < 4; ++dt)
#pragma unroll
        for (int r = 0; r < 4; ++r)
            atomicAdd(Ob + (size_t)n * ND + dt * 16 + qd * 4 + r, oacc[dt][r]);
}

extern "C" void kernel_launch(void* const* d_in, const int* in_sizes, int n_in,
                              void* d_out, int out_size, void* d_ws, size_t ws_size,
                              hipStream_t stream)
{
    const float* q    = (const float*)d_in[0];
    const float* k    = (const float*)d_in[1];
    const float* v    = (const float*)d_in[2];
    const float* bias = (const float*)d_in[3];
    float* out  = (float*)d_out;                      // [B,T,D]
    float* attn = out + (size_t)NB * NT * ND;         // [B,T,T]

    const size_t elems = (size_t)NB * NT * ND;        // 2M
    const size_t need  = 3 * elems * 2 + (size_t)NB * NT * 4;

    if (ws_size >= need) {
        unsigned short* qbf = (unsigned short*)d_ws;
        unsigned short* kbf = qbf + elems;
        unsigned short* vtb = kbf + elems;
        float* rsum = (float*)(vtb + elems);
        prep_k<<<dim3((unsigned)(elems / 4 / 256), 3), 256, 0, stream>>>(q, k, v, qbf, kbf, vtb);
        rowsum_k<<<dim3(NT / 16, NB), 256, 0, stream>>>(qbf, kbf, bias, rsum);
        attn_pv_k<<<dim3(NT / 16, NB), 256, 0, stream>>>(qbf, kbf, vtb, bias, rsum, out, attn);
    } else {
        hipMemsetAsync(out, 0, (size_t)NB * NT * ND * sizeof(float), stream);
        dim3 grid(NT / 16, NB);
        attn_fused<<<grid, 256, 0, stream>>>(q, k, v, bias, out, attn);
    }
}